// Round 1
// baseline (79.653 us; speedup 1.0000x reference)
//
#include <hip/hip_runtime.h>

#define NIMG 16
#define NRBF 128
#define ROWS 256
#define COLS 256
#define PIX  (ROWS * COLS)
#define PPT  4      // pixels per thread (consecutive columns)
#define TPB  256    // threads per block
#define BLKS_PER_IMG (PIX / (TPB * PPT))   // 64

__global__ __launch_bounds__(TPB) void rbf_image_kernel(
    const float* __restrict__ centers,      // (NIMG, NRBF, 2)
    const float* __restrict__ covariances,  // (NIMG, NRBF, 3)
    const float* __restrict__ amplitudes,   // (NIMG, NRBF, 1)
    float* __restrict__ out)                // (NIMG, ROWS, COLS)
{
    __shared__ float4 prm[NRBF];   // (cx, cy, m = -inv_two_sig2*log2e, amp)

    const int tid = threadIdx.x;
    const int img = blockIdx.x >> 6;       // / BLKS_PER_IMG
    const int blk = blockIdx.x & 63;       // % BLKS_PER_IMG

    const float LOG2E = 1.4426950408889634f;

    if (tid < NRBF) {
        const int k = tid;
        const float cx = centers[(img * NRBF + k) * 2 + 0];
        const float cy = centers[(img * NRBF + k) * 2 + 1];
        const float c0 = covariances[(img * NRBF + k) * 3 + 0];
        const float a  = amplitudes[img * NRBF + k];
        // sigma = exp(c0); inv_two_sig2 = 0.5/sigma^2 = 0.5*exp(-2*c0)
        const float inv2s2 = 0.5f * __builtin_amdgcn_exp2f(-2.0f * c0 * LOG2E);
        prm[k] = make_float4(cx, cy, -inv2s2 * LOG2E, a);
    }
    __syncthreads();

    // 4 consecutive pixels along a row per thread -> shared dy^2, float4 store
    const int p0 = blk * (TPB * PPT) + tid * PPT;
    const float y  = (float)(p0 >> 8);     // row
    const float x0 = (float)(p0 & 255);    // first column

    float acc0 = 0.f, acc1 = 0.f, acc2 = 0.f, acc3 = 0.f;

#pragma unroll 4
    for (int k = 0; k < NRBF; ++k) {
        const float4 p = prm[k];           // LDS broadcast (uniform addr)
        const float dy  = y - p.y;
        const float dy2 = dy * dy;
        const float dx0 = x0 - p.x;
        const float dx1 = dx0 + 1.0f;
        const float dx2 = dx0 + 2.0f;
        const float dx3 = dx0 + 3.0f;
        const float t0 = fmaf(dx0, dx0, dy2) * p.z;
        const float t1 = fmaf(dx1, dx1, dy2) * p.z;
        const float t2 = fmaf(dx2, dx2, dy2) * p.z;
        const float t3 = fmaf(dx3, dx3, dy2) * p.z;
        acc0 = fmaf(p.w, __builtin_amdgcn_exp2f(t0), acc0);
        acc1 = fmaf(p.w, __builtin_amdgcn_exp2f(t1), acc1);
        acc2 = fmaf(p.w, __builtin_amdgcn_exp2f(t2), acc2);
        acc3 = fmaf(p.w, __builtin_amdgcn_exp2f(t3), acc3);
    }

    // sigmoid(v) = 1 / (1 + exp(-v)) = rcp(1 + exp2(-v*log2e))
    float4 o;
    o.x = __builtin_amdgcn_rcpf(1.0f + __builtin_amdgcn_exp2f(-acc0 * LOG2E));
    o.y = __builtin_amdgcn_rcpf(1.0f + __builtin_amdgcn_exp2f(-acc1 * LOG2E));
    o.z = __builtin_amdgcn_rcpf(1.0f + __builtin_amdgcn_exp2f(-acc2 * LOG2E));
    o.w = __builtin_amdgcn_rcpf(1.0f + __builtin_amdgcn_exp2f(-acc3 * LOG2E));

    *(float4*)(out + img * PIX + p0) = o;
}

extern "C" void kernel_launch(void* const* d_in, const int* in_sizes, int n_in,
                              void* d_out, int out_size, void* d_ws, size_t ws_size,
                              hipStream_t stream) {
    const float* centers     = (const float*)d_in[0];
    const float* covariances = (const float*)d_in[1];
    const float* amplitudes  = (const float*)d_in[2];
    float* out = (float*)d_out;

    dim3 grid(NIMG * BLKS_PER_IMG);   // 1024 blocks
    dim3 block(TPB);
    rbf_image_kernel<<<grid, block, 0, stream>>>(centers, covariances, amplitudes, out);
}

// Round 2
// 76.282 us; speedup vs baseline: 1.0442x; 1.0442x over previous
//
#include <hip/hip_runtime.h>

#define NIMG 16
#define NRBF 128
#define ROWS 256
#define COLS 256
#define PIX  (ROWS * COLS)
#define TPB  256
#define ROWS_PER_BLK 8                       // 256 thr * 8 px = 2048 px = 8 rows
#define BLKS_PER_IMG (ROWS / ROWS_PER_BLK)   // 32

__global__ __launch_bounds__(TPB) void rbf_image_kernel(
    const float* __restrict__ centers,      // (NIMG, NRBF, 2)
    const float* __restrict__ covariances,  // (NIMG, NRBF, 3)
    const float* __restrict__ amplitudes,   // (NIMG, NRBF, 1)
    float* __restrict__ out)                // (NIMG, ROWS, COLS)
{
    // prm = (nscx = -s*cx, nscy = -s*cy, s, amp), s = sqrt(0.5*log2e)*exp(-c0)
    // so g = exp2(-((s*x + nscx)^2 + (s*y + nscy)^2)); neg is a free v_exp modifier
    __shared__ float4 prm[NRBF];

    const int tid = threadIdx.x;
    const int img = blockIdx.x >> 5;       // / BLKS_PER_IMG
    const int blk = blockIdx.x & 31;       // % BLKS_PER_IMG

    const float LOG2E = 1.4426950408889634f;

    if (tid < NRBF) {
        const int k = tid;
        const float cx = centers[(img * NRBF + k) * 2 + 0];
        const float cy = centers[(img * NRBF + k) * 2 + 1];
        const float c0 = covariances[(img * NRBF + k) * 3 + 0];
        const float a  = amplitudes[img * NRBF + k];
        // s = sqrt(0.5*log2(e)) * exp(-c0) ; sqrt(0.5*1.4426950408889634)=0.8493218002880190
        const float s = 0.8493218002880190f * __builtin_amdgcn_exp2f(-c0 * LOG2E);
        prm[k] = make_float4(-s * cx, -s * cy, s, a);
    }
    __syncthreads();

    // thread tile: 4 consecutive cols x 2 consecutive rows
    const int col  = (tid & 63) * 4;
    const int rowl = (tid >> 6) * 2;
    const int row  = blk * ROWS_PER_BLK + rowl;
    const float x0 = (float)col;
    const float y0 = (float)row;

    float aA0 = 0.f, aA1 = 0.f, aA2 = 0.f, aA3 = 0.f;
    float aB0 = 0.f, aB1 = 0.f, aB2 = 0.f, aB3 = 0.f;

#pragma unroll 4
    for (int k = 0; k < NRBF; ++k) {
        const float4 p = prm[k];           // LDS broadcast, ds_read_b128
        const float s = p.z;
        const float dx0 = fmaf(x0, s, p.x);   // s*(x-cx)
        const float dx1 = dx0 + s;
        const float dx2 = dx1 + s;
        const float dx3 = dx2 + s;
        const float dyA = fmaf(y0, s, p.y);   // s*(y-cy), row r
        const float dyB = dyA + s;            // row r+1
        const float dy2A = dyA * dyA;
        const float dy2B = dyB * dyB;

        const float eA0 = __builtin_amdgcn_exp2f(-fmaf(dx0, dx0, dy2A));
        const float eA1 = __builtin_amdgcn_exp2f(-fmaf(dx1, dx1, dy2A));
        const float eA2 = __builtin_amdgcn_exp2f(-fmaf(dx2, dx2, dy2A));
        const float eA3 = __builtin_amdgcn_exp2f(-fmaf(dx3, dx3, dy2A));
        const float eB0 = __builtin_amdgcn_exp2f(-fmaf(dx0, dx0, dy2B));
        const float eB1 = __builtin_amdgcn_exp2f(-fmaf(dx1, dx1, dy2B));
        const float eB2 = __builtin_amdgcn_exp2f(-fmaf(dx2, dx2, dy2B));
        const float eB3 = __builtin_amdgcn_exp2f(-fmaf(dx3, dx3, dy2B));

        aA0 = fmaf(p.w, eA0, aA0);
        aA1 = fmaf(p.w, eA1, aA1);
        aA2 = fmaf(p.w, eA2, aA2);
        aA3 = fmaf(p.w, eA3, aA3);
        aB0 = fmaf(p.w, eB0, aB0);
        aB1 = fmaf(p.w, eB1, aB1);
        aB2 = fmaf(p.w, eB2, aB2);
        aB3 = fmaf(p.w, eB3, aB3);
    }

    // sigmoid(v) = rcp(1 + exp2(-v*log2e))
    float4 oA, oB;
    oA.x = __builtin_amdgcn_rcpf(1.0f + __builtin_amdgcn_exp2f(-aA0 * LOG2E));
    oA.y = __builtin_amdgcn_rcpf(1.0f + __builtin_amdgcn_exp2f(-aA1 * LOG2E));
    oA.z = __builtin_amdgcn_rcpf(1.0f + __builtin_amdgcn_exp2f(-aA2 * LOG2E));
    oA.w = __builtin_amdgcn_rcpf(1.0f + __builtin_amdgcn_exp2f(-aA3 * LOG2E));
    oB.x = __builtin_amdgcn_rcpf(1.0f + __builtin_amdgcn_exp2f(-aB0 * LOG2E));
    oB.y = __builtin_amdgcn_rcpf(1.0f + __builtin_amdgcn_exp2f(-aB1 * LOG2E));
    oB.z = __builtin_amdgcn_rcpf(1.0f + __builtin_amdgcn_exp2f(-aB2 * LOG2E));
    oB.w = __builtin_amdgcn_rcpf(1.0f + __builtin_amdgcn_exp2f(-aB3 * LOG2E));

    float* base = out + img * PIX + row * COLS + col;
    *(float4*)(base)        = oA;   // lanes 0..63 cover one full row: coalesced
    *(float4*)(base + COLS) = oB;
}

extern "C" void kernel_launch(void* const* d_in, const int* in_sizes, int n_in,
                              void* d_out, int out_size, void* d_ws, size_t ws_size,
                              hipStream_t stream) {
    const float* centers     = (const float*)d_in[0];
    const float* covariances = (const float*)d_in[1];
    const float* amplitudes  = (const float*)d_in[2];
    float* out = (float*)d_out;

    dim3 grid(NIMG * BLKS_PER_IMG);   // 512 blocks
    dim3 block(TPB);
    rbf_image_kernel<<<grid, block, 0, stream>>>(centers, covariances, amplitudes, out);
}

// Round 3
// 66.910 us; speedup vs baseline: 1.1904x; 1.1401x over previous
//
#include <hip/hip_runtime.h>

#define NIMG 16
#define NRBF 128
#define ROWS 256
#define COLS 256
#define PIX  (ROWS * COLS)
#define TPB  256
#define RPB  8                     // rows per block strip
#define BLKS_PER_IMG (ROWS / RPB)  // 32
#define KC   32                    // k-chunk
#define NCHUNK (NRBF / KC)         // 4

// Separable RBF: exp(-(dx^2+dy^2)) = exp(-dx^2) * exp(-dy^2).
// val[y][x] = sum_k (a_k * gy[k][y]) * gx[k][x]  -> rank-128 outer-product,
// 1 fma per (pixel,k) in the hot loop instead of 3 VALU + 1 transcendental.
__global__ __launch_bounds__(TPB) void rbf_sep_kernel(
    const float* __restrict__ centers,      // (NIMG, NRBF, 2)
    const float* __restrict__ covariances,  // (NIMG, NRBF, 3)
    const float* __restrict__ amplitudes,   // (NIMG, NRBF, 1)
    float* __restrict__ out)                // (NIMG, ROWS, COLS)
{
    __shared__ float4 prm[NRBF];        // (nscx, nscy, s, a)
    __shared__ float  gx_s[KC][COLS];   // 32 KB: column factors for chunk
    __shared__ float  ga_s[KC][RPB];    // 1 KB: a * row factors for chunk

    const int tid = threadIdx.x;
    const int img = blockIdx.x >> 5;    // / BLKS_PER_IMG
    const int blk = blockIdx.x & 31;    // % BLKS_PER_IMG
    const int rb  = blk * RPB;

    const float LOG2E = 1.4426950408889634f;

    if (tid < NRBF) {
        const int k = tid;
        const float cx = centers[(img * NRBF + k) * 2 + 0];
        const float cy = centers[(img * NRBF + k) * 2 + 1];
        const float c0 = covariances[(img * NRBF + k) * 3 + 0];
        const float a  = amplitudes[img * NRBF + k];
        // s = sqrt(0.5*log2e)*exp(-c0): folds 0.5/sigma^2 and log2e into coords
        const float s = 0.8493218002880190f * __builtin_amdgcn_exp2f(-c0 * LOG2E);
        prm[k] = make_float4(-s * cx, -s * cy, s, a);
    }

    // thread tile for phase 2: 4 cols x 2 rows
    const int x0 = (tid & 63) * 4;      // wave-contiguous columns
    const int y0 = (tid >> 6) * 2;      // wave-uniform row pair

    // phase-1 assignments
    const float xf  = (float)tid;       // thread t -> column t for gx
    const int   kk1 = tid >> 3;         // thread t -> (k=t>>3, y=t&7) for ga
    const int   yy1 = tid & 7;
    const float yf  = (float)(rb + yy1);

    float aA0 = 0.f, aA1 = 0.f, aA2 = 0.f, aA3 = 0.f;
    float aB0 = 0.f, aB1 = 0.f, aB2 = 0.f, aB3 = 0.f;

    for (int c = 0; c < NCHUNK; ++c) {
        const int kb = c * KC;
        __syncthreads();  // prm ready (c==0); prior chunk's reads done (c>0)

        // phase 1a: gx[kk][x] = exp2(-(s*x + nscx)^2), one column per thread
#pragma unroll 8
        for (int kk = 0; kk < KC; ++kk) {
            const float4 p = prm[kb + kk];            // LDS broadcast
            const float dx = fmaf(xf, p.z, p.x);
            gx_s[kk][tid] = __builtin_amdgcn_exp2f(-dx * dx);
        }
        // phase 1b: ga[kk][y] = a * exp2(-(s*y + nscy)^2)
        {
            const float4 p = prm[kb + kk1];
            const float dy = fmaf(yf, p.z, p.y);
            ga_s[kk1][yy1] = p.w * __builtin_amdgcn_exp2f(-dy * dy);
        }
        __syncthreads();

        // phase 2: rank-KC outer-product accumulation, 8 fma / k / thread
#pragma unroll 8
        for (int kk = 0; kk < KC; ++kk) {
            const float4 g = *(const float4*)&gx_s[kk][x0];  // ds_read_b128, conflict-free
            const float2 w = *(const float2*)&ga_s[kk][y0];  // wave-uniform broadcast b64
            aA0 = fmaf(w.x, g.x, aA0);
            aA1 = fmaf(w.x, g.y, aA1);
            aA2 = fmaf(w.x, g.z, aA2);
            aA3 = fmaf(w.x, g.w, aA3);
            aB0 = fmaf(w.y, g.x, aB0);
            aB1 = fmaf(w.y, g.y, aB1);
            aB2 = fmaf(w.y, g.z, aB2);
            aB3 = fmaf(w.y, g.w, aB3);
        }
    }

    // sigmoid(v) = rcp(1 + exp2(-v*log2e))
    float4 oA, oB;
    oA.x = __builtin_amdgcn_rcpf(1.0f + __builtin_amdgcn_exp2f(-aA0 * LOG2E));
    oA.y = __builtin_amdgcn_rcpf(1.0f + __builtin_amdgcn_exp2f(-aA1 * LOG2E));
    oA.z = __builtin_amdgcn_rcpf(1.0f + __builtin_amdgcn_exp2f(-aA2 * LOG2E));
    oA.w = __builtin_amdgcn_rcpf(1.0f + __builtin_amdgcn_exp2f(-aA3 * LOG2E));
    oB.x = __builtin_amdgcn_rcpf(1.0f + __builtin_amdgcn_exp2f(-aB0 * LOG2E));
    oB.y = __builtin_amdgcn_rcpf(1.0f + __builtin_amdgcn_exp2f(-aB1 * LOG2E));
    oB.z = __builtin_amdgcn_rcpf(1.0f + __builtin_amdgcn_exp2f(-aB2 * LOG2E));
    oB.w = __builtin_amdgcn_rcpf(1.0f + __builtin_amdgcn_exp2f(-aB3 * LOG2E));

    float* base = out + img * PIX + (rb + y0) * COLS + x0;
    *(float4*)(base)        = oA;   // wave covers a full row: coalesced 1 KB
    *(float4*)(base + COLS) = oB;
}

extern "C" void kernel_launch(void* const* d_in, const int* in_sizes, int n_in,
                              void* d_out, int out_size, void* d_ws, size_t ws_size,
                              hipStream_t stream) {
    const float* centers     = (const float*)d_in[0];
    const float* covariances = (const float*)d_in[1];
    const float* amplitudes  = (const float*)d_in[2];
    float* out = (float*)d_out;

    dim3 grid(NIMG * BLKS_PER_IMG);   // 512 blocks -> 2 blocks/CU
    dim3 block(TPB);
    rbf_sep_kernel<<<grid, block, 0, stream>>>(centers, covariances, amplitudes, out);
}

// Round 4
// 66.047 us; speedup vs baseline: 1.2060x; 1.0131x over previous
//
#include <hip/hip_runtime.h>

#define NIMG 16
#define NRBF 128
#define ROWS 256
#define COLS 256
#define PIX  (ROWS * COLS)
#define TPB  256
#define RPB  16                    // rows per block strip
#define BLKS_PER_IMG (ROWS / RPB)  // 16
#define KC   32                    // k-chunk
#define NCHUNK (NRBF / KC)         // 4

// Separable RBF, rank-128 outer product: val[y][x] = sum_k (a_k*gy[k][y])*gx[k][x].
// Thread tile 4 cols x 4 rows: one 16B gx read feeds 16 fma (LDS bytes/fma = 1),
// balancing the LDS pipe (~128 B/cyc/CU) against the VALU fma floor.
__global__ __launch_bounds__(TPB) void rbf_sep_kernel(
    const float* __restrict__ centers,      // (NIMG, NRBF, 2)
    const float* __restrict__ covariances,  // (NIMG, NRBF, 3)
    const float* __restrict__ amplitudes,   // (NIMG, NRBF, 1)
    float* __restrict__ out)                // (NIMG, ROWS, COLS)
{
    __shared__ float4 prm[NRBF];        // (nscx, nscy, s, a)           2 KB
    __shared__ float  gx_s[KC][COLS];   // column factors, chunk       32 KB
    __shared__ float  ga_s[KC][RPB];    // a * row factors, chunk       2 KB

    const int tid = threadIdx.x;
    const int img = blockIdx.x >> 4;    // / BLKS_PER_IMG
    const int blk = blockIdx.x & 15;    // % BLKS_PER_IMG
    const int rb  = blk * RPB;

    const float LOG2E = 1.4426950408889634f;

    if (tid < NRBF) {
        const int k = tid;
        const float cx = centers[(img * NRBF + k) * 2 + 0];
        const float cy = centers[(img * NRBF + k) * 2 + 1];
        const float c0 = covariances[(img * NRBF + k) * 3 + 0];
        const float a  = amplitudes[img * NRBF + k];
        // s = sqrt(0.5*log2e)*exp(-c0): folds 0.5/sigma^2 and log2e into coords
        const float s = 0.8493218002880190f * __builtin_amdgcn_exp2f(-c0 * LOG2E);
        prm[k] = make_float4(-s * cx, -s * cy, s, a);
    }

    // phase-2 thread tile: 4 cols x 4 rows
    const int x0 = (tid & 63) * 4;      // wave covers a full 256-col row
    const int y0 = (tid >> 6) * 4;      // wave-uniform

    // phase-1 assignments
    const float xf  = (float)tid;       // gx: thread t -> column t
    const int   kk1 = tid >> 4;         // ga: (k=t>>4 and k=t>>4+16, y=t&15)
    const int   yy1 = tid & 15;
    const float yf  = (float)(rb + yy1);

    float aA0=0.f,aA1=0.f,aA2=0.f,aA3=0.f;
    float aB0=0.f,aB1=0.f,aB2=0.f,aB3=0.f;
    float aC0=0.f,aC1=0.f,aC2=0.f,aC3=0.f;
    float aD0=0.f,aD1=0.f,aD2=0.f,aD3=0.f;

    for (int c = 0; c < NCHUNK; ++c) {
        const int kb = c * KC;
        __syncthreads();  // prm ready (c==0); prior chunk's reads done (c>0)

        // phase 1a: gx[kk][x] = exp2(-(s*x + nscx)^2)
#pragma unroll 8
        for (int kk = 0; kk < KC; ++kk) {
            const float4 p = prm[kb + kk];            // LDS broadcast
            const float dx = fmaf(xf, p.z, p.x);
            gx_s[kk][tid] = __builtin_amdgcn_exp2f(-dx * dx);
        }
        // phase 1b: ga[kk][y] = a * exp2(-(s*y + nscy)^2); 2 slots/thread
        {
            const float4 p0 = prm[kb + kk1];
            const float dy0 = fmaf(yf, p0.z, p0.y);
            ga_s[kk1][yy1] = p0.w * __builtin_amdgcn_exp2f(-dy0 * dy0);
            const float4 p1 = prm[kb + kk1 + 16];
            const float dy1 = fmaf(yf, p1.z, p1.y);
            ga_s[kk1 + 16][yy1] = p1.w * __builtin_amdgcn_exp2f(-dy1 * dy1);
        }
        __syncthreads();

        // phase 2: 16 fma per k per thread off one b128 + one broadcast b128
#pragma unroll 8
        for (int kk = 0; kk < KC; ++kk) {
            const float4 g = *(const float4*)&gx_s[kk][x0];  // conflict-free b128
            const float4 w = *(const float4*)&ga_s[kk][y0];  // wave-uniform broadcast
            aA0 = fmaf(w.x, g.x, aA0); aA1 = fmaf(w.x, g.y, aA1);
            aA2 = fmaf(w.x, g.z, aA2); aA3 = fmaf(w.x, g.w, aA3);
            aB0 = fmaf(w.y, g.x, aB0); aB1 = fmaf(w.y, g.y, aB1);
            aB2 = fmaf(w.y, g.z, aB2); aB3 = fmaf(w.y, g.w, aB3);
            aC0 = fmaf(w.z, g.x, aC0); aC1 = fmaf(w.z, g.y, aC1);
            aC2 = fmaf(w.z, g.z, aC2); aC3 = fmaf(w.z, g.w, aC3);
            aD0 = fmaf(w.w, g.x, aD0); aD1 = fmaf(w.w, g.y, aD1);
            aD2 = fmaf(w.w, g.z, aD2); aD3 = fmaf(w.w, g.w, aD3);
        }
    }

    // sigmoid(v) = rcp(1 + exp2(-v*log2e))
#define SIG(v) __builtin_amdgcn_rcpf(1.0f + __builtin_amdgcn_exp2f(-(v) * LOG2E))
    float4 oA = { SIG(aA0), SIG(aA1), SIG(aA2), SIG(aA3) };
    float4 oB = { SIG(aB0), SIG(aB1), SIG(aB2), SIG(aB3) };
    float4 oC = { SIG(aC0), SIG(aC1), SIG(aC2), SIG(aC3) };
    float4 oD = { SIG(aD0), SIG(aD1), SIG(aD2), SIG(aD3) };
#undef SIG

    float* base = out + img * PIX + (rb + y0) * COLS + x0;
    *(float4*)(base)            = oA;   // each wave writes a full row: coalesced
    *(float4*)(base + COLS)     = oB;
    *(float4*)(base + 2 * COLS) = oC;
    *(float4*)(base + 3 * COLS) = oD;
}

extern "C" void kernel_launch(void* const* d_in, const int* in_sizes, int n_in,
                              void* d_out, int out_size, void* d_ws, size_t ws_size,
                              hipStream_t stream) {
    const float* centers     = (const float*)d_in[0];
    const float* covariances = (const float*)d_in[1];
    const float* amplitudes  = (const float*)d_in[2];
    float* out = (float*)d_out;

    dim3 grid(NIMG * BLKS_PER_IMG);   // 256 blocks -> 1 block/CU
    dim3 block(TPB);
    rbf_sep_kernel<<<grid, block, 0, stream>>>(centers, covariances, amplitudes, out);
}

// Round 5
// 65.978 us; speedup vs baseline: 1.2073x; 1.0010x over previous
//
#include <hip/hip_runtime.h>

#define NIMG 16
#define NRBF 128
#define ROWS 256
#define COLS 256
#define PIX  (ROWS * COLS)
#define TPB  256
#define RPB  16                    // rows per block strip
#define BLKS_PER_IMG (ROWS / RPB)  // 16
#define KC   32                    // k-chunk
#define NCHUNK (NRBF / KC)         // 4

// Separable RBF, rank-128 outer product, with EXACT sparsity skipping:
// centers ~ N(0,1), sigma in [1,e) -> fp32 exp underflows to exactly 0 beyond
// ~40 px from a center, so ~99% of (wave,chunk) tiles contribute exactly 0.
// Wave w owns cols [64w,64w+64): phase-1a thread t computes col t, so wave w's
// ballot over its own gx slice is a wave-uniform skip flag. A block-level LDS
// flag covers "all row factors zero". Skipping is exact (sum of a*0).
__global__ __launch_bounds__(TPB) void rbf_sep_kernel(
    const float* __restrict__ centers,      // (NIMG, NRBF, 2)
    const float* __restrict__ covariances,  // (NIMG, NRBF, 3)
    const float* __restrict__ amplitudes,   // (NIMG, NRBF, 1)
    float* __restrict__ out)                // (NIMG, ROWS, COLS)
{
    __shared__ float4 prm[NRBF];        // (nscx, nscy, s, a)           2 KB
    __shared__ float  gx_s[KC][COLS];   // column factors, chunk       32 KB
    __shared__ float  ga_s[KC][RPB];    // a * row factors, chunk       2 KB
    __shared__ int    ga_nz[NCHUNK];    // block-level "any row factor nonzero"

    const int tid  = threadIdx.x;
    const int wave = tid >> 6;
    const int lane = tid & 63;
    const int img  = blockIdx.x >> 4;   // / BLKS_PER_IMG
    const int blk  = blockIdx.x & 15;   // % BLKS_PER_IMG
    const int rb   = blk * RPB;

    const float LOG2E = 1.4426950408889634f;

    if (tid < NRBF) {
        const int k = tid;
        const float cx = centers[(img * NRBF + k) * 2 + 0];
        const float cy = centers[(img * NRBF + k) * 2 + 1];
        const float c0 = covariances[(img * NRBF + k) * 3 + 0];
        const float a  = amplitudes[img * NRBF + k];
        // s = sqrt(0.5*log2e)*exp(-c0): folds 0.5/sigma^2 and log2e into coords
        const float s = 0.8493218002880190f * __builtin_amdgcn_exp2f(-c0 * LOG2E);
        prm[k] = make_float4(-s * cx, -s * cy, s, a);
    }
    if (tid < NCHUNK) ga_nz[tid] = 0;

    // phase-2 thread tile: 4 cols x 4 rows; wave w owns cols [64w, 64w+64)
    const int x0 = wave * 64 + (lane & 15) * 4;
    const int y0 = (lane >> 4) * 4;

    // phase-1 assignments
    const float xf  = (float)tid;       // gx: thread t -> column t (wave-aligned)
    const int   kk1 = tid >> 4;         // ga: (k = t>>4 and t>>4+16, y = t&15)
    const int   yy1 = tid & 15;
    const float yf  = (float)(rb + yy1);

    float aA0=0.f,aA1=0.f,aA2=0.f,aA3=0.f;
    float aB0=0.f,aB1=0.f,aB2=0.f,aB3=0.f;
    float aC0=0.f,aC1=0.f,aC2=0.f,aC3=0.f;
    float aD0=0.f,aD1=0.f,aD2=0.f,aD3=0.f;

    for (int c = 0; c < NCHUNK; ++c) {
        const int kb = c * KC;
        __syncthreads();  // prm/ga_nz ready (c==0); prior chunk's reads done

        // phase 1a: gx[kk][x] = exp2(-(s*x + nscx)^2); track per-col nonzero
        bool colnz = false;
#pragma unroll 8
        for (int kk = 0; kk < KC; ++kk) {
            const float4 p = prm[kb + kk];            // LDS broadcast
            const float dx = fmaf(xf, p.z, p.x);
            const float v  = __builtin_amdgcn_exp2f(-dx * dx);
            gx_s[kk][tid] = v;
            colnz = colnz || (v > 0.0f);
        }
        const bool wave_has_x = (__ballot(colnz) != 0ULL);  // wave-uniform

        // phase 1b: ga[kk][y] = a * exp2(-(s*y + nscy)^2); 2 slots/thread
        {
            const float4 p0 = prm[kb + kk1];
            const float dy0 = fmaf(yf, p0.z, p0.y);
            const float g0  = __builtin_amdgcn_exp2f(-dy0 * dy0);
            ga_s[kk1][yy1] = p0.w * g0;
            const float4 p1 = prm[kb + kk1 + 16];
            const float dy1 = fmaf(yf, p1.z, p1.y);
            const float g1  = __builtin_amdgcn_exp2f(-dy1 * dy1);
            ga_s[kk1 + 16][yy1] = p1.w * g1;
            if (g0 > 0.0f || g1 > 0.0f) ga_nz[c] = 1;  // race-benign set
        }
        __syncthreads();

        // phase 2: skip if this wave's columns or the strip's rows are all zero
        if (wave_has_x && ga_nz[c]) {
#pragma unroll 8
            for (int kk = 0; kk < KC; ++kk) {
                const float4 g = *(const float4*)&gx_s[kk][x0];  // 2-way max (free)
                const float4 w = *(const float4*)&ga_s[kk][y0];  // broadcast
                aA0 = fmaf(w.x, g.x, aA0); aA1 = fmaf(w.x, g.y, aA1);
                aA2 = fmaf(w.x, g.z, aA2); aA3 = fmaf(w.x, g.w, aA3);
                aB0 = fmaf(w.y, g.x, aB0); aB1 = fmaf(w.y, g.y, aB1);
                aB2 = fmaf(w.y, g.z, aB2); aB3 = fmaf(w.y, g.w, aB3);
                aC0 = fmaf(w.z, g.x, aC0); aC1 = fmaf(w.z, g.y, aC1);
                aC2 = fmaf(w.z, g.z, aC2); aC3 = fmaf(w.z, g.w, aC3);
                aD0 = fmaf(w.w, g.x, aD0); aD1 = fmaf(w.w, g.y, aD1);
                aD2 = fmaf(w.w, g.z, aD2); aD3 = fmaf(w.w, g.w, aD3);
            }
        }
    }

    // sigmoid(v) = rcp(1 + exp2(-v*log2e)); acc==0 -> exactly 0.5 like the ref
#define SIG(v) __builtin_amdgcn_rcpf(1.0f + __builtin_amdgcn_exp2f(-(v) * LOG2E))
    float4 oA = { SIG(aA0), SIG(aA1), SIG(aA2), SIG(aA3) };
    float4 oB = { SIG(aB0), SIG(aB1), SIG(aB2), SIG(aB3) };
    float4 oC = { SIG(aC0), SIG(aC1), SIG(aC2), SIG(aC3) };
    float4 oD = { SIG(aD0), SIG(aD1), SIG(aD2), SIG(aD3) };
#undef SIG

    float* base = out + img * PIX + (rb + y0) * COLS + x0;
    *(float4*)(base)            = oA;   // 16 lanes x 16 B = 256 B segments
    *(float4*)(base + COLS)     = oB;
    *(float4*)(base + 2 * COLS) = oC;
    *(float4*)(base + 3 * COLS) = oD;
}

extern "C" void kernel_launch(void* const* d_in, const int* in_sizes, int n_in,
                              void* d_out, int out_size, void* d_ws, size_t ws_size,
                              hipStream_t stream) {
    const float* centers     = (const float*)d_in[0];
    const float* covariances = (const float*)d_in[1];
    const float* amplitudes  = (const float*)d_in[2];
    float* out = (float*)d_out;

    dim3 grid(NIMG * BLKS_PER_IMG);   // 256 blocks -> 1 block/CU
    dim3 block(TPB);
    rbf_sep_kernel<<<grid, block, 0, stream>>>(centers, covariances, amplitudes, out);
}

// Round 6
// 60.646 us; speedup vs baseline: 1.3134x; 1.0879x over previous
//
#include <hip/hip_runtime.h>

#define NIMG 16
#define NRBF 128
#define ROWS 256
#define COLS 256
#define PIX  (ROWS * COLS)
#define TPB  256
#define RPB  16                    // rows per block strip
#define BLKS_PER_IMG (ROWS / RPB)  // 16
#define KC   64                    // k-chunk (2 chunks of 64)
#define KSTR 72                    // padded k-stride in halfs (144 B, 16B-aligned)

typedef _Float16 f16x8 __attribute__((ext_vector_type(8)));
typedef float    f32x4 __attribute__((ext_vector_type(4)));

// Separable RBF as a rank-128 GEMM on the matrix cores:
//   C[y][x] = sum_k (a_k * gy[k][y]) * gx[k][x]
// A = ga^T [row][k] (f16), B = gxT [col][k] (f16), mfma_f32_16x16x32_f16.
// Frag layouts (verified m89/m91/m120): A/B lane l -> [free=l&15][k=(l>>4)*8+j];
// C/D lane l -> col=l&15, row=(l>>4)*4+reg.
__global__ __launch_bounds__(TPB) void rbf_mfma_kernel(
    const float* __restrict__ centers,      // (NIMG, NRBF, 2)
    const float* __restrict__ covariances,  // (NIMG, NRBF, 3)
    const float* __restrict__ amplitudes,   // (NIMG, NRBF, 1)
    float* __restrict__ out)                // (NIMG, ROWS, COLS)
{
    __shared__ _Float16 gxT[COLS][KSTR];   // B tile: [col][k]   36,864 B
    __shared__ _Float16 gaT[RPB][KSTR];    // A tile: [row][k]    2,304 B
    __shared__ float2   pxs[NRBF];         // (nscx, s)           1,024 B
    __shared__ float4   pya[NRBF];         // (nscy, s, a, 0)     2,048 B

    const int tid  = threadIdx.x;
    const int lane = tid & 63;
    const int wave = tid >> 6;
    const int img  = blockIdx.x >> 4;   // / BLKS_PER_IMG
    const int blk  = blockIdx.x & 15;   // % BLKS_PER_IMG
    const int rb   = blk * RPB;

    const float LOG2E = 1.4426950408889634f;

    if (tid < NRBF) {
        const int k = tid;
        const float cx = centers[(img * NRBF + k) * 2 + 0];
        const float cy = centers[(img * NRBF + k) * 2 + 1];
        const float c0 = covariances[(img * NRBF + k) * 3 + 0];
        const float a  = amplitudes[img * NRBF + k];
        // s = sqrt(0.5*log2e)*exp(-c0): folds 0.5/sigma^2 and log2e into coords
        const float s = 0.8493218002880190f * __builtin_amdgcn_exp2f(-c0 * LOG2E);
        pxs[k] = make_float2(-s * cx, s);
        pya[k] = make_float4(-s * cy, s, a, 0.0f);
    }

    // phase-2 lane roles
    const int n  = lane & 15;          // C col within tile / B free idx / A row idx
    const int q  = lane >> 4;          // quad -> k-run base q*8
    const int col0 = wave * 64;        // wave owns 4 ctiles: cols 64w + 16i

    f32x4 acc0 = {0,0,0,0}, acc1 = {0,0,0,0}, acc2 = {0,0,0,0}, acc3 = {0,0,0,0};

    const float xf = (float)tid;       // phase-1a: thread t -> column t
    const int   m1  = tid & 15;        // phase-1b: row
    const int   k1  = (tid >> 4) * 4;  // phase-1b: 4-k run
    const float yf  = (float)(rb + m1);

    for (int c = 0; c < 2; ++c) {
        const int kb_g = c * KC;
        __syncthreads();  // params ready (c==0); prior chunk's frags consumed (c==1)

        // phase 1a: gxT[tid][kk] = (f16)exp2(-(s*x+nscx)^2), 8 k per b128 write
#pragma unroll
        for (int k8 = 0; k8 < KC / 8; ++k8) {
            f16x8 h;
#pragma unroll
            for (int j = 0; j < 8; ++j) {
                const float2 p = pxs[kb_g + k8 * 8 + j];   // LDS broadcast b64
                const float dx = fmaf(xf, p.y, p.x);
                h[j] = (_Float16)__builtin_amdgcn_exp2f(-dx * dx);
            }
            *(f16x8*)&gxT[tid][k8 * 8] = h;
        }
        // phase 1b: gaT[m][k] = (f16)(a * exp2(-(s*y+nscy)^2)), 4 k per thread
        {
            _Float16 h[4];
#pragma unroll
            for (int j = 0; j < 4; ++j) {
                const float4 p = pya[kb_g + k1 + j];
                const float dy = fmaf(yf, p.y, p.x);
                h[j] = (_Float16)(p.z * __builtin_amdgcn_exp2f(-dy * dy));
            }
            *(__attribute__((ext_vector_type(4))) _Float16*)&gaT[m1][k1] =
                *(__attribute__((ext_vector_type(4))) _Float16*)h;
        }
        __syncthreads();

        // phase 2: 2 x (K=32) mfma steps over this chunk, 4 ctiles per wave
#pragma unroll
        for (int kc = 0; kc < 2; ++kc) {
            const int kb = kc * 32 + q * 8;
            const f16x8 afr = *(const f16x8*)&gaT[n][kb];
            const f16x8 b0  = *(const f16x8*)&gxT[col0 +  0 + n][kb];
            const f16x8 b1  = *(const f16x8*)&gxT[col0 + 16 + n][kb];
            const f16x8 b2  = *(const f16x8*)&gxT[col0 + 32 + n][kb];
            const f16x8 b3  = *(const f16x8*)&gxT[col0 + 48 + n][kb];
            acc0 = __builtin_amdgcn_mfma_f32_16x16x32_f16(afr, b0, acc0, 0, 0, 0);
            acc1 = __builtin_amdgcn_mfma_f32_16x16x32_f16(afr, b1, acc1, 0, 0, 0);
            acc2 = __builtin_amdgcn_mfma_f32_16x16x32_f16(afr, b2, acc2, 0, 0, 0);
            acc3 = __builtin_amdgcn_mfma_f32_16x16x32_f16(afr, b3, acc3, 0, 0, 0);
        }
    }

    // epilogue: sigmoid + store. C/D: col = n, row = q*4 + r.
#define SIG(v) __builtin_amdgcn_rcpf(1.0f + __builtin_amdgcn_exp2f(-(v) * LOG2E))
    float* base = out + img * PIX + rb * COLS + n + col0;
#pragma unroll
    for (int r = 0; r < 4; ++r) {
        float* rp = base + (q * 4 + r) * COLS;
        rp[0]  = SIG(acc0[r]);
        rp[16] = SIG(acc1[r]);
        rp[32] = SIG(acc2[r]);
        rp[48] = SIG(acc3[r]);
    }
#undef SIG
}

extern "C" void kernel_launch(void* const* d_in, const int* in_sizes, int n_in,
                              void* d_out, int out_size, void* d_ws, size_t ws_size,
                              hipStream_t stream) {
    const float* centers     = (const float*)d_in[0];
    const float* covariances = (const float*)d_in[1];
    const float* amplitudes  = (const float*)d_in[2];
    float* out = (float*)d_out;

    dim3 grid(NIMG * BLKS_PER_IMG);   // 256 blocks -> 1 block/CU
    dim3 block(TPB);
    rbf_mfma_kernel<<<grid, block, 0, stream>>>(centers, covariances, amplitudes, out);
}

// Round 7
// 59.466 us; speedup vs baseline: 1.3395x; 1.0198x over previous
//
#include <hip/hip_runtime.h>

#define NIMG 16
#define NRBF 128
#define ROWS 256
#define COLS 256
#define PIX  (ROWS * COLS)
#define TPB  256
#define TILE 64                    // 64x64 px per block
#define TPI  16                    // tiles per image (4x4)
#define KSTR 136                   // padded k-stride in halfs (272 B, 16B-aligned)

typedef _Float16 f16x8 __attribute__((ext_vector_type(8)));
typedef float    f32x4 __attribute__((ext_vector_type(4)));

// Separable RBF as a rank-128 GEMM on matrix cores, 64x64-px square tiles:
//   C[y][x] = sum_k (a_k * gy[k][y]) * gx[k][x]
// Square tile minimizes phase-1 transcendental work: 64 exps/thread
// (64 cols + 64 rows, K=128) vs 136 for a 16x256 strip. Full K in LDS,
// one barrier pair, 16 mfma/wave. Frag layouts verified (m89/m91):
// A/B lane l -> [free=l&15][k=(l>>4)*8+j]; C/D col=l&15, row=(l>>4)*4+reg.
__global__ __launch_bounds__(TPB) void rbf_mfma_kernel(
    const float* __restrict__ centers,      // (NIMG, NRBF, 2)
    const float* __restrict__ covariances,  // (NIMG, NRBF, 3)
    const float* __restrict__ amplitudes,   // (NIMG, NRBF, 1)
    float* __restrict__ out)                // (NIMG, ROWS, COLS)
{
    __shared__ _Float16 gxT[TILE][KSTR];   // B tile: [col][k]   17,408 B
    __shared__ _Float16 gaT[TILE][KSTR];   // A tile: [row][k]   17,408 B
    __shared__ float2   pxs[NRBF];         // (nscx, s)           1,024 B
    __shared__ float4   pya[NRBF];         // (nscy, s, a, 0)     2,048 B

    const int tid  = threadIdx.x;
    const int lane = tid & 63;
    const int wave = tid >> 6;
    const int img  = blockIdx.x >> 4;      // / TPI
    const int tile = blockIdx.x & 15;      // % TPI
    const int rb   = (tile >> 2) * TILE;   // tile row base
    const int cb   = (tile & 3) * TILE;    // tile col base

    const float LOG2E = 1.4426950408889634f;

    if (tid < NRBF) {
        const int k = tid;
        const float cx = centers[(img * NRBF + k) * 2 + 0];
        const float cy = centers[(img * NRBF + k) * 2 + 1];
        const float c0 = covariances[(img * NRBF + k) * 3 + 0];
        const float a  = amplitudes[img * NRBF + k];
        // s = sqrt(0.5*log2e)*exp(-c0): folds 0.5/sigma^2 and log2e into coords
        const float s = 0.8493218002880190f * __builtin_amdgcn_exp2f(-c0 * LOG2E);
        pxs[k] = make_float2(-s * cx, s);
        pya[k] = make_float4(-s * cy, s, a, 0.0f);
    }
    __syncthreads();

    // phase 1: thread t -> col/row (t&63), k-range [(t>>6)*32, +32)
    const int   cc  = tid & 63;
    const int   kb0 = (tid >> 6) * 32;
    const float xf  = (float)(cb + cc);
    const float yf  = (float)(rb + cc);

#pragma unroll
    for (int k8 = 0; k8 < 4; ++k8) {       // 32 k per thread, b128 writes
        const int kb = kb0 + k8 * 8;
        f16x8 hx, ha;
#pragma unroll
        for (int j = 0; j < 8; ++j) {
            const float2 px = pxs[kb + j];             // LDS broadcast
            const float dx = fmaf(xf, px.y, px.x);
            hx[j] = (_Float16)__builtin_amdgcn_exp2f(-dx * dx);
            const float4 py = pya[kb + j];
            const float dy = fmaf(yf, py.y, py.x);
            ha[j] = (_Float16)(py.z * __builtin_amdgcn_exp2f(-dy * dy));
        }
        *(f16x8*)&gxT[cc][kb] = hx;
        *(f16x8*)&gaT[cc][kb] = ha;
    }
    __syncthreads();

    // phase 2: wave w -> rows [16w,16w+16), 4 ctiles over cols; 16 mfma total
    const int n = lane & 15;
    const int q = lane >> 4;

    f32x4 acc0 = {0,0,0,0}, acc1 = {0,0,0,0}, acc2 = {0,0,0,0}, acc3 = {0,0,0,0};

#pragma unroll
    for (int kc = 0; kc < 4; ++kc) {
        const int kb = kc * 32 + q * 8;
        const f16x8 afr = *(const f16x8*)&gaT[wave * 16 + n][kb];
        const f16x8 b0  = *(const f16x8*)&gxT[ 0 + n][kb];
        const f16x8 b1  = *(const f16x8*)&gxT[16 + n][kb];
        const f16x8 b2  = *(const f16x8*)&gxT[32 + n][kb];
        const f16x8 b3  = *(const f16x8*)&gxT[48 + n][kb];
        acc0 = __builtin_amdgcn_mfma_f32_16x16x32_f16(afr, b0, acc0, 0, 0, 0);
        acc1 = __builtin_amdgcn_mfma_f32_16x16x32_f16(afr, b1, acc1, 0, 0, 0);
        acc2 = __builtin_amdgcn_mfma_f32_16x16x32_f16(afr, b2, acc2, 0, 0, 0);
        acc3 = __builtin_amdgcn_mfma_f32_16x16x32_f16(afr, b3, acc3, 0, 0, 0);
    }

    // epilogue: sigmoid + store. C/D: col = n (within ctile), row = q*4 + r.
#define SIG(v) __builtin_amdgcn_rcpf(1.0f + __builtin_amdgcn_exp2f(-(v) * LOG2E))
    float* base = out + img * PIX + (rb + wave * 16) * COLS + cb + n;
#pragma unroll
    for (int r = 0; r < 4; ++r) {
        float* rp = base + (q * 4 + r) * COLS;
        rp[0]  = SIG(acc0[r]);
        rp[16] = SIG(acc1[r]);
        rp[32] = SIG(acc2[r]);
        rp[48] = SIG(acc3[r]);
    }
#undef SIG
}

extern "C" void kernel_launch(void* const* d_in, const int* in_sizes, int n_in,
                              void* d_out, int out_size, void* d_ws, size_t ws_size,
                              hipStream_t stream) {
    const float* centers     = (const float*)d_in[0];
    const float* covariances = (const float*)d_in[1];
    const float* amplitudes  = (const float*)d_in[2];
    float* out = (float*)d_out;

    dim3 grid(NIMG * TPI);   // 256 blocks -> 1 block/CU
    dim3 block(TPB);
    rbf_mfma_kernel<<<grid, block, 0, stream>>>(centers, covariances, amplitudes, out);
}